// Round 8
// baseline (564.049 us; speedup 1.0000x reference)
//
#include <hip/hip_runtime.h>
#include <cstdint>
#include <math.h>

#define NBATCH 8
#define NANCH 262144
#define TOPK 6000
#define OUTK 1000
#define CAP 16384
#define ROWS 6016          // TOPK padded to 94*64
#define WORDS 94           // ceil(6000/64)
#define NT 4465            // upper-tri tiles: 94*95/2

using u32 = uint32_t;
using u64 = unsigned long long;

// ---------------- coarse top-k threshold: one 12-bit histogram pass ----------------
__global__ void hist_kernel(const float* __restrict__ cls, u32* __restrict__ hist) {
    __shared__ u32 lh[4096];
    int b = blockIdx.y, t = threadIdx.x;
    for (int i = t; i < 4096; i += 256) lh[i] = 0;
    __syncthreads();
    const float4* p4 = (const float4*)(cls + (size_t)b * NANCH * 2);
    const int P = NANCH / 2;
    for (int p = blockIdx.x * 256 + t; p < P; p += gridDim.x * 256) {
        float4 v = p4[p];
        atomicAdd(&lh[__float_as_uint(v.y) >> 20], 1);
        atomicAdd(&lh[__float_as_uint(v.w) >> 20], 1);
    }
    __syncthreads();
    for (int i = t; i < 4096; i += 256) { u32 c = lh[i]; if (c) atomicAdd(&hist[b * 4096 + i], c); }
}

// ---------------- compact: inline threshold scan + LDS staging, 1 atomic/block ----------
__global__ void compact_kernel(const float* __restrict__ cls, const u32* __restrict__ hist,
                               u32* __restrict__ meta, u64* __restrict__ cand) {
    __shared__ u64 buf[4096];
    __shared__ u32 ts[256];
    __shared__ u32 thr, lc, gbase;
    int b = blockIdx.y, t = threadIdx.x;
    if (t == 0) lc = 0;
    const u32* h = hist + b * 4096;
    u32 s = 0;
    for (int k = 0; k < 16; k++) s += h[t * 16 + k];
    ts[t] = s; __syncthreads();
    u32 suf = 0;
    for (int t2 = t + 1; t2 < 256; t2++) suf += ts[t2];
    if (suf < TOPK && suf + s >= TOPK) {
        u32 a = suf;
        for (int k = 15; k >= 0; k--) {
            u32 c = h[t * 16 + k];
            if (a + c >= TOPK) { thr = (u32)(t * 16 + k) << 20; break; }
            a += c;
        }
    }
    __syncthreads();
    u32 T = thr;
    const float4* p4 = (const float4*)(cls + (size_t)b * NANCH * 2);
    const int P = NANCH / 2;
    for (int p = blockIdx.x * 256 + t; p < P; p += gridDim.x * 256) {
        float4 v = p4[p];
        u32 k0 = __float_as_uint(v.y), k1 = __float_as_uint(v.w);
        u32 n0 = 2u * (u32)p, n1 = n0 + 1u;
        if (k0 >= T) { u32 q = atomicAdd(&lc, 1u); buf[q] = ((u64)k0 << 32) | (u32)(~n0); }
        if (k1 >= T) { u32 q = atomicAdd(&lc, 1u); buf[q] = ((u64)k1 << 32) | (u32)(~n1); }
    }
    __syncthreads();
    if (t == 0) gbase = atomicAdd(&meta[48 + b], lc);
    __syncthreads();
    u32 base = gbase, n = lc;
    for (u32 j = t; j < n; j += 256) {
        u32 d = base + j;
        if (d < CAP) cand[(size_t)b * CAP + d] = buf[j];
    }
}

// ---------------- cross-lane helpers ----------------
__device__ inline u64 shfl64(u64 x, int src) {
    int lo = __shfl((int)(u32)(x & 0xffffffffull), src, 64);
    int hi = __shfl((int)(u32)(x >> 32), src, 64);
    return ((u64)(u32)hi << 32) | (u32)lo;
}
__device__ inline u64 readlane64(u64 x, int sl) {
    u32 lo = (u32)__builtin_amdgcn_readlane((int)(u32)x, sl);
    u32 hi = (u32)__builtin_amdgcn_readlane((int)(u32)(x >> 32), sl);
    return ((u64)hi << 32) | lo;
}
__device__ inline u64 wave_or64(u64 x) {
    u32 lo = (u32)x, hi = (u32)(x >> 32);
    lo |= __builtin_amdgcn_ds_swizzle(lo, 0x041F); hi |= __builtin_amdgcn_ds_swizzle(hi, 0x041F);
    lo |= __builtin_amdgcn_ds_swizzle(lo, 0x081F); hi |= __builtin_amdgcn_ds_swizzle(hi, 0x081F);
    lo |= __builtin_amdgcn_ds_swizzle(lo, 0x101F); hi |= __builtin_amdgcn_ds_swizzle(hi, 0x101F);
    lo |= __builtin_amdgcn_ds_swizzle(lo, 0x201F); hi |= __builtin_amdgcn_ds_swizzle(hi, 0x201F);
    lo |= __builtin_amdgcn_ds_swizzle(lo, 0x401F); hi |= __builtin_amdgcn_ds_swizzle(hi, 0x401F);
    u32 l0 = (u32)__builtin_amdgcn_readlane((int)lo, 0)  | (u32)__builtin_amdgcn_readlane((int)lo, 32);
    u32 h0 = (u32)__builtin_amdgcn_readlane((int)hi, 0)  | (u32)__builtin_amdgcn_readlane((int)hi, 32);
    return ((u64)h0 << 32) | l0;
}

// ---------------- exact stable rank via 64-lane ring rotation; writes boxes+areas -------
__global__ void rank_kernel(const u64* __restrict__ cand, const u32* __restrict__ meta,
                            const float* __restrict__ anchors, const float* __restrict__ bbox,
                            float4* __restrict__ boxes, float* __restrict__ areas) {
    __shared__ u64 tile[2048];
    int b = blockIdx.y, t = threadIdx.x, l = t & 63;
    int c0 = blockIdx.x * 256 + t;
    u32 cnt = meta[48 + b]; if (cnt > CAP) cnt = CAP;
    if (blockIdx.x == 0 && t < ROWS - TOPK) {   // zero-pad rows 6000..6015
        boxes[(size_t)b * ROWS + TOPK + t] = make_float4(0.f, 0.f, 0.f, 0.f);
        areas[(size_t)b * ROWS + TOPK + t] = 0.f;
    }
    if (blockIdx.x * 256 >= (int)cnt) return;
    const u64* cb = cand + (size_t)b * CAP;
    u64 Kc = (c0 < (int)cnt) ? cb[c0] : 0ull;
    u32 rank = 0;
    for (u32 t0 = 0; t0 < cnt; t0 += 2048) {
        for (int q = t; q < 2048; q += 256)
            tile[q] = (t0 + (u32)q < cnt) ? cb[t0 + q] : 0ull;
        __syncthreads();
        u64 r[32];
        #pragma unroll
        for (int u = 0; u < 32; u++) r[u] = tile[l + (u << 6)];
        u64 kk = Kc; u32 cc = 0;
        for (int s = 0; s < 64; s++) {
            #pragma unroll
            for (int u = 0; u < 32; u++) cc += (r[u] > kk) ? 1u : 0u;
            int src = (l + 1) & 63;
            kk = shfl64(kk, src);
            cc = (u32)__shfl((int)cc, src, 64);
        }
        rank += cc;
        __syncthreads();
    }
    if (c0 < (int)cnt && rank < TOPK) {
        u32 idx = ~(u32)(Kc & 0xFFFFFFFFull);
        size_t off = ((size_t)b * NANCH + idx) * 4;
        const float4 a = *(const float4*)(anchors + off);
        const float4 d = *(const float4*)(bbox + off);
        float h = a.z - a.x, w = a.w - a.y;
        float cy = a.x + 0.5f * h, cx = a.y + 0.5f * w;
        float dy = d.x * 0.1f, dx = d.y * 0.1f, dh = d.z * 0.2f, dw = d.w * 0.2f;
        cy = cy + dy * h; cx = cx + dx * w;
        h = h * (float)exp((double)dh);
        w = w * (float)exp((double)dw);
        float y1 = cy - 0.5f * h, x1 = cx - 0.5f * w;
        float y2 = cy + 0.5f * h, x2 = cx + 0.5f * w;
        y1 = fminf(fmaxf(y1, 0.f), 1.f); x1 = fminf(fmaxf(x1, 0.f), 1.f);
        y2 = fminf(fmaxf(y2, 0.f), 1.f); x2 = fminf(fmaxf(x2, 0.f), 1.f);
        boxes[(size_t)b * ROWS + rank] = make_float4(y1, x1, y2, x2);
        areas[(size_t)b * ROWS + rank] = (y2 - y1) * (x2 - x1);  // same rounding as reference
    }
}

// ---------------- NMS phase A: 1 wave per upper-tri tile, dbuf scalar col prefetch -------
// Exact decision: RN(inter/uni) > 0.7f  <=>  inter >= MID*uni (reals), MID = 0.7f + 2^-25.
// Fast f32 path: d = fma(uni,-0.7f,inter); |d| > 2^-18*uni => sign decides. Waves with any
// borderline col (rare) redo the whole tile with an exact-sign f64 fma.
__global__ __launch_bounds__(256, 4) void nms_mask_kernel(const float4* __restrict__ boxes,
                                                          const float* __restrict__ areas,
                                                          u64* __restrict__ Mt) {
    const float  EPS  = 3.8146972656e-06f;                       // 2^-18
    const double MIDD = (double)0.7f + 2.9802322387695312e-08;   // midpoint to nextup(0.7f)
    int b = blockIdx.y;
    int tid = blockIdx.x * 4 + (threadIdx.x >> 6);               // linear upper-tri tile id
    int l = threadIdx.x & 63;
    if (tid >= NT) return;
    // decode tid -> (cb, rt), rt <= cb, tid = cb*(cb+1)/2 + rt
    int cb = (int)((sqrt(8.0 * (double)tid + 1.0) - 1.0) * 0.5);
    while ((cb + 1) * (cb + 2) / 2 <= tid) cb++;
    while (cb * (cb + 1) / 2 > tid) cb--;
    int rt = tid - cb * (cb + 1) / 2;
    const float4* bx = boxes + (size_t)b * ROWS;
    const float*  ar = areas + (size_t)b * ROWS;
    int row = rt * 64 + l;
    float4 r4 = bx[row];                         // lane l = row rt*64+l (vector load)
    float  rar = ar[row];
    const float4* cbp = bx + cb * 64;            // cols: uniform-indexed -> scalar loads
    const float*  cap = ar + cb * 64;
    float4 cA[8], cB[8]; float aA[8], aB[8];
    #pragma unroll
    for (int i = 0; i < 8; i++) { cA[i] = cbp[56 + i]; aA[i] = cap[56 + i]; }   // blk 7
    u32 wlo = 0, whi = 0; u64 unc = 0;
    #pragma unroll
    for (int blk = 7; blk >= 0; blk--) {         // cols 63..0, shift-or accumulation
        bool useA = ((7 - blk) & 1) == 0;
        if (blk > 0) {                           // prefetch blk-1 into the other buffer
            #pragma unroll
            for (int i = 0; i < 8; i++) {
                if (useA) { cB[i] = cbp[(blk - 1) * 8 + i]; aB[i] = cap[(blk - 1) * 8 + i]; }
                else      { cA[i] = cbp[(blk - 1) * 8 + i]; aA[i] = cap[(blk - 1) * 8 + i]; }
            }
        }
        #pragma unroll
        for (int i = 7; i >= 0; i--) {
            int c = blk * 8 + i;
            float4 c4 = useA ? cA[i] : cB[i];
            float  caf = useA ? aA[i] : aB[i];
            float y1 = fmaxf(r4.x, c4.x), x1 = fmaxf(r4.y, c4.y);
            float y2 = fminf(r4.z, c4.z), x2 = fminf(r4.w, c4.w);
            float inter = fmaxf(y2 - y1, 0.f) * fmaxf(x2 - x1, 0.f);
            float uni = ((rar + caf) - inter) + 1e-9f;   // assoc matches reference
            float d = fmaf(uni, -0.7f, inter);
            float tt = uni * EPS;
            u32 sup = (d > tt) ? 1u : 0u;
            unc |= __ballot(fabsf(d) <= tt);
            if (c >= 32) whi = (whi << 1) | sup;
            else         wlo = (wlo << 1) | sup;
        }
    }
    if (unc) {                                   // wave-uniform, rare
        wlo = 0; whi = 0;
        for (int c = 63; c >= 0; c--) {
            float4 cc4 = cbp[c]; float caf = cap[c];
            float y1 = fmaxf(r4.x, cc4.x), x1 = fmaxf(r4.y, cc4.y);
            float y2 = fminf(r4.z, cc4.z), x2 = fminf(r4.w, cc4.w);
            float inter = fmaxf(y2 - y1, 0.f) * fmaxf(x2 - x1, 0.f);
            float uni = ((rar + caf) - inter) + 1e-9f;
            double td = fma((double)uni, -MIDD, (double)inter);
            u32 sup = (td >= 0.0) ? 1u : 0u;     // exact sign; tie -> suppress (RN ties up)
            if (c >= 32) whi = (whi << 1) | sup;
            else         wlo = (wlo << 1) | sup;
        }
    }
    u64 w = ((u64)whi << 32) | wlo;
    if (cb == rt) w &= (l < 63) ? (~0ull << (l + 1)) : 0ull;   // cols > row only
    Mt[((size_t)b * WORDS + cb) * ROWS + row] = w;             // coalesced full-line store
}

// ---------------- NMS phase B: scalar-unit greedy, swizzle reduce, 2-deep prefetch -------
__global__ __launch_bounds__(64) void nms_seq_kernel(const float4* __restrict__ boxes,
                                                     const u64* __restrict__ Mt,
                                                     float* __restrict__ out) {
    __shared__ u32 keptIdx[1024];
    int b = blockIdx.x, l = threadIdx.x;
    const u64* Mb = Mt + (size_t)b * WORDS * ROWS;    // Mb[word*ROWS + row]
    const float4* bx = boxes + (size_t)b * ROWS;
    float4* ob = (float4*)(out + (size_t)b * OUTK * 4);
    int kept = 0;
    u64 rw = 0;
    u64 dw0 = Mb[l];                                  // diag word of chunk 0
    float4 vb0 = bx[l];
    u64 X0 = Mb[(size_t)ROWS + l];                    // chunk-0 rows -> word 1
    u64 dw1 = Mb[(size_t)ROWS + 64 + l];              // diag word of chunk 1
    float4 vb1 = bx[64 + l];
    u64 X1 = Mb[(size_t)2 * ROWS + 64 + l];           // chunk-1 rows -> word 2
    u64 gp = 0;
    for (int c = 0; c < WORDS; c++) {
        int base = c * 64;
        u64 valid = (base + 64 <= TOPK) ? ~0ull : ((1ull << (TOPK - base)) - 1);
        u64 alive = ~rw & valid;
        u64 km = 0, xk = 0; int kt = kept;
        while (alive && kt < OUTK) {                  // greedy: SALU/readlane only
            int j = __builtin_amdgcn_readfirstlane((int)__builtin_ctzll(alive));
            km |= 1ull << j; kt++;
            u64 dwj = readlane64(dw0, j);
            xk |= readlane64(X0, j);
            alive &= ~dwj & ~(1ull << j);
        }
        if ((km >> l) & 1) {
            int pos = kept + __popcll(km & ((1ull << l) - 1));
            ob[pos] = vb0;
            keptIdx[pos] = (u32)(base + l);
        }
        kept = kt;
        if (kept >= OUTK || c + 1 >= WORDS) break;
        rw = xk | wave_or64(gp);
        __syncthreads();
        u64 dw2 = 0, X2 = 0; float4 vb2 = make_float4(0.f, 0.f, 0.f, 0.f);
        u64 gpn = 0;
        if (c + 2 < WORDS) {
            int nb2 = base + 128;
            dw2 = Mb[(size_t)(c + 2) * ROWS + nb2 + l];
            vb2 = bx[nb2 + l];
            if (c + 3 < WORDS) X2 = Mb[(size_t)(c + 3) * ROWS + nb2 + l];
            int K = kept;
            if (K > 0) {
                #pragma unroll
                for (int u = 0; u < 16; u++) {
                    int k = l + (u << 6);
                    u32 idx = keptIdx[(k < K) ? k : K - 1];
                    gpn |= Mb[(size_t)(c + 2) * ROWS + idx];
                }
            }
        }
        dw0 = dw1; X0 = X1; vb0 = vb1;
        dw1 = dw2; X1 = X2; vb1 = vb2;
        gp = gpn;
    }
    // tail zeros (replaces d_out memset): positions [kept, OUTK)
    for (int p = kept + l; p < OUTK; p += 64)
        ob[p] = make_float4(0.f, 0.f, 0.f, 0.f);
}

// ---------------- host ----------------
extern "C" void kernel_launch(void* const* d_in, const int* in_sizes, int n_in,
                              void* d_out, int out_size, void* d_ws, size_t ws_size,
                              hipStream_t stream) {
    const float* cls     = (const float*)d_in[0];   // rpn_class  (B,N,2)
    const float* bbox    = (const float*)d_in[1];   // rpn_bbox   (B,N,4)
    const float* anchors = (const float*)d_in[2];   // anchors    (B,N,4)

    char* ws = (char*)d_ws;
    u32* hist1 = (u32*)(ws);                        // 131072
    u32* meta  = (u32*)(ws + 131072);               // 256 B (count @48+b)
    float4* boxes = (float4*)(ws + 131328);         // 8*6016*16 = 770048 -> end 901376
    float* areas  = (float*)(ws + 901376);          // 8*6016*4  = 192512 -> end 1093888
    u64* Mt = (u64*)(ws + 1093888);                 // 8*94*6016*8 = 36190208 -> end 37284096
    u64* cand = Mt;                                 // overlay: cand dead before Mt written
    size_t need = 1093888 + (size_t)NBATCH * WORDS * ROWS * 8;
    if (ws_size < need) return;

    hipMemsetAsync(ws, 0, 131328, stream);          // hist + meta

    hist_kernel<<<dim3(64, NBATCH), 256, 0, stream>>>(cls, hist1);
    compact_kernel<<<dim3(64, NBATCH), 256, 0, stream>>>(cls, hist1, meta, cand);
    rank_kernel<<<dim3(CAP / 256, NBATCH), 256, 0, stream>>>(cand, meta, anchors, bbox, boxes, areas);
    nms_mask_kernel<<<dim3((NT + 3) / 4, NBATCH), 256, 0, stream>>>(boxes, areas, Mt);
    nms_seq_kernel<<<NBATCH, 64, 0, stream>>>(boxes, Mt, (float*)d_out);
}

// Round 9
// 398.160 us; speedup vs baseline: 1.4166x; 1.4166x over previous
//
#include <hip/hip_runtime.h>
#include <cstdint>
#include <math.h>

#define NBATCH 8
#define NANCH 262144
#define TOPK 6000
#define OUTK 1000
#define CAP 16384
#define ROWS 6016          // TOPK padded to 94*64
#define WORDS 94           // ceil(6000/64)
#define NT 4465            // upper-tri tiles: 94*95/2

using u32 = uint32_t;
using u64 = unsigned long long;

// ---------------- coarse top-k threshold: one 12-bit histogram pass ----------------
__global__ void hist_kernel(const float* __restrict__ cls, u32* __restrict__ hist) {
    __shared__ u32 lh[4096];
    int b = blockIdx.y, t = threadIdx.x;
    for (int i = t; i < 4096; i += 256) lh[i] = 0;
    __syncthreads();
    const float4* p4 = (const float4*)(cls + (size_t)b * NANCH * 2);
    const int P = NANCH / 2;
    for (int p = blockIdx.x * 256 + t; p < P; p += gridDim.x * 256) {
        float4 v = p4[p];
        atomicAdd(&lh[__float_as_uint(v.y) >> 20], 1);
        atomicAdd(&lh[__float_as_uint(v.w) >> 20], 1);
    }
    __syncthreads();
    for (int i = t; i < 4096; i += 256) { u32 c = lh[i]; if (c) atomicAdd(&hist[b * 4096 + i], c); }
}

// ---------------- compact: inline threshold scan + LDS staging, 1 atomic/block ----------
__global__ void compact_kernel(const float* __restrict__ cls, const u32* __restrict__ hist,
                               u32* __restrict__ meta, u64* __restrict__ cand) {
    __shared__ u64 buf[4096];
    __shared__ u32 ts[256];
    __shared__ u32 thr, lc, gbase;
    int b = blockIdx.y, t = threadIdx.x;
    if (t == 0) lc = 0;
    const u32* h = hist + b * 4096;
    u32 s = 0;
    for (int k = 0; k < 16; k++) s += h[t * 16 + k];
    ts[t] = s; __syncthreads();
    u32 suf = 0;
    for (int t2 = t + 1; t2 < 256; t2++) suf += ts[t2];
    if (suf < TOPK && suf + s >= TOPK) {
        u32 a = suf;
        for (int k = 15; k >= 0; k--) {
            u32 c = h[t * 16 + k];
            if (a + c >= TOPK) { thr = (u32)(t * 16 + k) << 20; break; }
            a += c;
        }
    }
    __syncthreads();
    u32 T = thr;
    const float4* p4 = (const float4*)(cls + (size_t)b * NANCH * 2);
    const int P = NANCH / 2;
    for (int p = blockIdx.x * 256 + t; p < P; p += gridDim.x * 256) {
        float4 v = p4[p];
        u32 k0 = __float_as_uint(v.y), k1 = __float_as_uint(v.w);
        u32 n0 = 2u * (u32)p, n1 = n0 + 1u;
        if (k0 >= T) { u32 q = atomicAdd(&lc, 1u); buf[q] = ((u64)k0 << 32) | (u32)(~n0); }
        if (k1 >= T) { u32 q = atomicAdd(&lc, 1u); buf[q] = ((u64)k1 << 32) | (u32)(~n1); }
    }
    __syncthreads();
    if (t == 0) gbase = atomicAdd(&meta[48 + b], lc);
    __syncthreads();
    u32 base = gbase, n = lc;
    for (u32 j = t; j < n; j += 256) {
        u32 d = base + j;
        if (d < CAP) cand[(size_t)b * CAP + d] = buf[j];
    }
}

// ---------------- cross-lane helpers ----------------
__device__ inline u64 shfl64(u64 x, int src) {
    int lo = __shfl((int)(u32)(x & 0xffffffffull), src, 64);
    int hi = __shfl((int)(u32)(x >> 32), src, 64);
    return ((u64)(u32)hi << 32) | (u32)lo;
}
__device__ inline u64 readlane64(u64 x, int sl) {
    u32 lo = (u32)__builtin_amdgcn_readlane((int)(u32)x, sl);
    u32 hi = (u32)__builtin_amdgcn_readlane((int)(u32)(x >> 32), sl);
    return ((u64)hi << 32) | lo;
}
__device__ inline u64 wave_or64(u64 x) {
    u32 lo = (u32)x, hi = (u32)(x >> 32);
    lo |= __builtin_amdgcn_ds_swizzle(lo, 0x041F); hi |= __builtin_amdgcn_ds_swizzle(hi, 0x041F);
    lo |= __builtin_amdgcn_ds_swizzle(lo, 0x081F); hi |= __builtin_amdgcn_ds_swizzle(hi, 0x081F);
    lo |= __builtin_amdgcn_ds_swizzle(lo, 0x101F); hi |= __builtin_amdgcn_ds_swizzle(hi, 0x101F);
    lo |= __builtin_amdgcn_ds_swizzle(lo, 0x201F); hi |= __builtin_amdgcn_ds_swizzle(hi, 0x201F);
    lo |= __builtin_amdgcn_ds_swizzle(lo, 0x401F); hi |= __builtin_amdgcn_ds_swizzle(hi, 0x401F);
    u32 l0 = (u32)__builtin_amdgcn_readlane((int)lo, 0)  | (u32)__builtin_amdgcn_readlane((int)lo, 32);
    u32 h0 = (u32)__builtin_amdgcn_readlane((int)hi, 0)  | (u32)__builtin_amdgcn_readlane((int)hi, 32);
    return ((u64)h0 << 32) | l0;
}

// ---------------- exact stable rank via 64-lane ring rotation; writes boxes+areas -------
__global__ void rank_kernel(const u64* __restrict__ cand, const u32* __restrict__ meta,
                            const float* __restrict__ anchors, const float* __restrict__ bbox,
                            float4* __restrict__ boxes, float* __restrict__ areas) {
    __shared__ u64 tile[2048];
    int b = blockIdx.y, t = threadIdx.x, l = t & 63;
    int c0 = blockIdx.x * 256 + t;
    u32 cnt = meta[48 + b]; if (cnt > CAP) cnt = CAP;
    if (blockIdx.x == 0 && t < ROWS - TOPK) {   // zero-pad rows 6000..6015
        boxes[(size_t)b * ROWS + TOPK + t] = make_float4(0.f, 0.f, 0.f, 0.f);
        areas[(size_t)b * ROWS + TOPK + t] = 0.f;
    }
    if (blockIdx.x * 256 >= (int)cnt) return;
    const u64* cb = cand + (size_t)b * CAP;
    u64 Kc = (c0 < (int)cnt) ? cb[c0] : 0ull;
    u32 rank = 0;
    for (u32 t0 = 0; t0 < cnt; t0 += 2048) {
        for (int q = t; q < 2048; q += 256)
            tile[q] = (t0 + (u32)q < cnt) ? cb[t0 + q] : 0ull;
        __syncthreads();
        u64 r[32];
        #pragma unroll
        for (int u = 0; u < 32; u++) r[u] = tile[l + (u << 6)];
        u64 kk = Kc; u32 cc = 0;
        for (int s = 0; s < 64; s++) {
            #pragma unroll
            for (int u = 0; u < 32; u++) cc += (r[u] > kk) ? 1u : 0u;
            int src = (l + 1) & 63;
            kk = shfl64(kk, src);
            cc = (u32)__shfl((int)cc, src, 64);
        }
        rank += cc;
        __syncthreads();
    }
    if (c0 < (int)cnt && rank < TOPK) {
        u32 idx = ~(u32)(Kc & 0xFFFFFFFFull);
        size_t off = ((size_t)b * NANCH + idx) * 4;
        const float4 a = *(const float4*)(anchors + off);
        const float4 d = *(const float4*)(bbox + off);
        float h = a.z - a.x, w = a.w - a.y;
        float cy = a.x + 0.5f * h, cx = a.y + 0.5f * w;
        float dy = d.x * 0.1f, dx = d.y * 0.1f, dh = d.z * 0.2f, dw = d.w * 0.2f;
        cy = cy + dy * h; cx = cx + dx * w;
        h = h * (float)exp((double)dh);
        w = w * (float)exp((double)dw);
        float y1 = cy - 0.5f * h, x1 = cx - 0.5f * w;
        float y2 = cy + 0.5f * h, x2 = cx + 0.5f * w;
        y1 = fminf(fmaxf(y1, 0.f), 1.f); x1 = fminf(fmaxf(x1, 0.f), 1.f);
        y2 = fminf(fmaxf(y2, 0.f), 1.f); x2 = fminf(fmaxf(x2, 0.f), 1.f);
        boxes[(size_t)b * ROWS + rank] = make_float4(y1, x1, y2, x2);
        areas[(size_t)b * ROWS + rank] = (y2 - y1) * (x2 - x1);  // same rounding as reference
    }
}

// ---------------- NMS phase A: 1 wave/upper-tri tile, cols in LDS, spill-free -----------
// Exact decision: RN(inter/uni) > 0.7f  <=>  inter >= MID*uni (reals), MID = 0.7f + 2^-25.
// Fast f32 path: d = fma(uni,-0.7f,inter); |d| > 2^-18*uni => sign decides. Waves with any
// borderline col (rare) redo the whole tile with an exact-sign f64 fma.
__global__ __launch_bounds__(256) void nms_mask_kernel(const float4* __restrict__ boxes,
                                                       const float* __restrict__ areas,
                                                       u64* __restrict__ Mt) {
    const float  EPS  = 3.8146972656e-06f;                       // 2^-18
    const double MIDD = (double)0.7f + 2.9802322387695312e-08;   // midpoint to nextup(0.7f)
    __shared__ float4 scol[4][64];
    __shared__ float  sare[4][64];
    int b = blockIdx.y;
    int wv = threadIdx.x >> 6, l = threadIdx.x & 63;
    int tid = blockIdx.x * 4 + wv;                               // linear upper-tri tile id
    if (tid >= NT) return;                                       // wave-private LDS: safe
    // decode tid -> (cb, rt), rt <= cb, tid = cb*(cb+1)/2 + rt
    int cb = (int)((sqrt(8.0 * (double)tid + 1.0) - 1.0) * 0.5);
    while ((cb + 1) * (cb + 2) / 2 <= tid) cb++;
    while (cb * (cb + 1) / 2 > tid) cb--;
    int rt = tid - cb * (cb + 1) / 2;
    const float4* bx = boxes + (size_t)b * ROWS;
    const float*  ar = areas + (size_t)b * ROWS;
    // stage this wave's 64 col boxes into its private LDS slice (wave-synchronous)
    scol[wv][l] = bx[cb * 64 + l];
    sare[wv][l] = ar[cb * 64 + l];
    int row = rt * 64 + l;
    float4 r4 = bx[row];                         // lane l = row rt*64+l (vector load)
    float  rar = ar[row];
    u32 wlo = 0, whi = 0; u64 unc = 0;
    #pragma unroll
    for (int c = 63; c >= 0; c--) {              // full unroll, shift-or accumulation
        float4 c4 = scol[wv][c];                 // broadcast ds_read_b128 (no conflict)
        float  caf = sare[wv][c];
        float y1 = fmaxf(r4.x, c4.x), x1 = fmaxf(r4.y, c4.y);
        float y2 = fminf(r4.z, c4.z), x2 = fminf(r4.w, c4.w);
        float inter = fmaxf(y2 - y1, 0.f) * fmaxf(x2 - x1, 0.f);
        float uni = ((rar + caf) - inter) + 1e-9f;   // assoc matches reference
        float d = fmaf(uni, -0.7f, inter);
        float tt = uni * EPS;
        u32 sup = (d > tt) ? 1u : 0u;
        unc |= __ballot(fabsf(d) <= tt);
        if (c >= 32) whi = (whi << 1) | sup;
        else         wlo = (wlo << 1) | sup;
    }
    if (unc) {                                   // wave-uniform, rare
        wlo = 0; whi = 0;
        for (int c = 63; c >= 0; c--) {
            float4 c4 = scol[wv][c]; float caf = sare[wv][c];
            float y1 = fmaxf(r4.x, c4.x), x1 = fmaxf(r4.y, c4.y);
            float y2 = fminf(r4.z, c4.z), x2 = fminf(r4.w, c4.w);
            float inter = fmaxf(y2 - y1, 0.f) * fmaxf(x2 - x1, 0.f);
            float uni = ((rar + caf) - inter) + 1e-9f;
            double td = fma((double)uni, -MIDD, (double)inter);
            u32 sup = (td >= 0.0) ? 1u : 0u;     // exact sign; tie -> suppress (RN ties up)
            if (c >= 32) whi = (whi << 1) | sup;
            else         wlo = (wlo << 1) | sup;
        }
    }
    u64 w = ((u64)whi << 32) | wlo;
    if (cb == rt) w &= (l < 63) ? (~0ull << (l + 1)) : 0ull;   // cols > row only
    Mt[((size_t)b * WORDS + cb) * ROWS + row] = w;             // coalesced full-line store
}

// ---------------- NMS phase B: scalar-unit greedy, swizzle reduce, 2-deep prefetch -------
__global__ __launch_bounds__(64) void nms_seq_kernel(const float4* __restrict__ boxes,
                                                     const u64* __restrict__ Mt,
                                                     float* __restrict__ out) {
    __shared__ u32 keptIdx[1024];
    int b = blockIdx.x, l = threadIdx.x;
    const u64* Mb = Mt + (size_t)b * WORDS * ROWS;    // Mb[word*ROWS + row]
    const float4* bx = boxes + (size_t)b * ROWS;
    float4* ob = (float4*)(out + (size_t)b * OUTK * 4);
    int kept = 0;
    u64 rw = 0;
    u64 dw0 = Mb[l];                                  // diag word of chunk 0
    float4 vb0 = bx[l];
    u64 X0 = Mb[(size_t)ROWS + l];                    // chunk-0 rows -> word 1
    u64 dw1 = Mb[(size_t)ROWS + 64 + l];              // diag word of chunk 1
    float4 vb1 = bx[64 + l];
    u64 X1 = Mb[(size_t)2 * ROWS + 64 + l];           // chunk-1 rows -> word 2
    u64 gp = 0;
    for (int c = 0; c < WORDS; c++) {
        int base = c * 64;
        u64 valid = (base + 64 <= TOPK) ? ~0ull : ((1ull << (TOPK - base)) - 1);
        u64 alive = ~rw & valid;
        u64 km = 0, xk = 0; int kt = kept;
        while (alive && kt < OUTK) {                  // greedy: SALU/readlane only
            int j = __builtin_amdgcn_readfirstlane((int)__builtin_ctzll(alive));
            km |= 1ull << j; kt++;
            u64 dwj = readlane64(dw0, j);
            xk |= readlane64(X0, j);
            alive &= ~dwj & ~(1ull << j);
        }
        if ((km >> l) & 1) {
            int pos = kept + __popcll(km & ((1ull << l) - 1));
            ob[pos] = vb0;
            keptIdx[pos] = (u32)(base + l);
        }
        kept = kt;
        if (kept >= OUTK || c + 1 >= WORDS) break;
        rw = xk | wave_or64(gp);
        __syncthreads();
        u64 dw2 = 0, X2 = 0; float4 vb2 = make_float4(0.f, 0.f, 0.f, 0.f);
        u64 gpn = 0;
        if (c + 2 < WORDS) {
            int nb2 = base + 128;
            dw2 = Mb[(size_t)(c + 2) * ROWS + nb2 + l];
            vb2 = bx[nb2 + l];
            if (c + 3 < WORDS) X2 = Mb[(size_t)(c + 3) * ROWS + nb2 + l];
            int K = kept;
            if (K > 0) {
                #pragma unroll
                for (int u = 0; u < 16; u++) {
                    int k = l + (u << 6);
                    u32 idx = keptIdx[(k < K) ? k : K - 1];
                    gpn |= Mb[(size_t)(c + 2) * ROWS + idx];
                }
            }
        }
        dw0 = dw1; X0 = X1; vb0 = vb1;
        dw1 = dw2; X1 = X2; vb1 = vb2;
        gp = gpn;
    }
    // tail zeros (replaces d_out memset): positions [kept, OUTK)
    for (int p = kept + l; p < OUTK; p += 64)
        ob[p] = make_float4(0.f, 0.f, 0.f, 0.f);
}

// ---------------- host ----------------
extern "C" void kernel_launch(void* const* d_in, const int* in_sizes, int n_in,
                              void* d_out, int out_size, void* d_ws, size_t ws_size,
                              hipStream_t stream) {
    const float* cls     = (const float*)d_in[0];   // rpn_class  (B,N,2)
    const float* bbox    = (const float*)d_in[1];   // rpn_bbox   (B,N,4)
    const float* anchors = (const float*)d_in[2];   // anchors    (B,N,4)

    char* ws = (char*)d_ws;
    u32* hist1 = (u32*)(ws);                        // 131072
    u32* meta  = (u32*)(ws + 131072);               // 256 B (count @48+b)
    float4* boxes = (float4*)(ws + 131328);         // 8*6016*16 = 770048 -> end 901376
    float* areas  = (float*)(ws + 901376);          // 8*6016*4  = 192512 -> end 1093888
    u64* Mt = (u64*)(ws + 1093888);                 // 8*94*6016*8 = 36190208 -> end 37284096
    u64* cand = Mt;                                 // overlay: cand dead before Mt written
    size_t need = 1093888 + (size_t)NBATCH * WORDS * ROWS * 8;
    if (ws_size < need) return;

    hipMemsetAsync(ws, 0, 131328, stream);          // hist + meta

    hist_kernel<<<dim3(64, NBATCH), 256, 0, stream>>>(cls, hist1);
    compact_kernel<<<dim3(64, NBATCH), 256, 0, stream>>>(cls, hist1, meta, cand);
    rank_kernel<<<dim3(CAP / 256, NBATCH), 256, 0, stream>>>(cand, meta, anchors, bbox, boxes, areas);
    nms_mask_kernel<<<dim3((NT + 3) / 4, NBATCH), 256, 0, stream>>>(boxes, areas, Mt);
    nms_seq_kernel<<<NBATCH, 64, 0, stream>>>(boxes, Mt, (float*)d_out);
}

// Round 10
// 304.311 us; speedup vs baseline: 1.8535x; 1.3084x over previous
//
#include <hip/hip_runtime.h>
#include <cstdint>
#include <math.h>

#define NBATCH 8
#define NANCH 262144
#define TOPK 6000
#define OUTK 1000
#define CAP 16384
#define ROWS 6016          // TOPK padded to 94*64 (boxes/areas stride)
#define MROWS 2048         // masked NMS window: rows/cols with precomputed mask
#define MWORDS 32          // MROWS/64
#define NT2 528            // upper-tri tiles in window: 32*33/2

using u32 = uint32_t;
using u64 = unsigned long long;

// ---------------- coarse top-k threshold: one 12-bit histogram pass ----------------
__global__ void hist_kernel(const float* __restrict__ cls, u32* __restrict__ hist) {
    __shared__ u32 lh[4096];
    int b = blockIdx.y, t = threadIdx.x;
    for (int i = t; i < 4096; i += 256) lh[i] = 0;
    __syncthreads();
    const float4* p4 = (const float4*)(cls + (size_t)b * NANCH * 2);
    const int P = NANCH / 2;
    for (int p = blockIdx.x * 256 + t; p < P; p += gridDim.x * 256) {
        float4 v = p4[p];
        atomicAdd(&lh[__float_as_uint(v.y) >> 20], 1);
        atomicAdd(&lh[__float_as_uint(v.w) >> 20], 1);
    }
    __syncthreads();
    for (int i = t; i < 4096; i += 256) { u32 c = lh[i]; if (c) atomicAdd(&hist[b * 4096 + i], c); }
}

// ---------------- compact: inline threshold scan + LDS staging, 1 atomic/block ----------
__global__ void compact_kernel(const float* __restrict__ cls, const u32* __restrict__ hist,
                               u32* __restrict__ meta, u64* __restrict__ cand) {
    __shared__ u64 buf[4096];
    __shared__ u32 ts[256];
    __shared__ u32 thr, lc, gbase;
    int b = blockIdx.y, t = threadIdx.x;
    if (t == 0) lc = 0;
    const u32* h = hist + b * 4096;
    u32 s = 0;
    for (int k = 0; k < 16; k++) s += h[t * 16 + k];
    ts[t] = s; __syncthreads();
    u32 suf = 0;
    for (int t2 = t + 1; t2 < 256; t2++) suf += ts[t2];
    if (suf < TOPK && suf + s >= TOPK) {
        u32 a = suf;
        for (int k = 15; k >= 0; k--) {
            u32 c = h[t * 16 + k];
            if (a + c >= TOPK) { thr = (u32)(t * 16 + k) << 20; break; }
            a += c;
        }
    }
    __syncthreads();
    u32 T = thr;
    const float4* p4 = (const float4*)(cls + (size_t)b * NANCH * 2);
    const int P = NANCH / 2;
    for (int p = blockIdx.x * 256 + t; p < P; p += gridDim.x * 256) {
        float4 v = p4[p];
        u32 k0 = __float_as_uint(v.y), k1 = __float_as_uint(v.w);
        u32 n0 = 2u * (u32)p, n1 = n0 + 1u;
        if (k0 >= T) { u32 q = atomicAdd(&lc, 1u); buf[q] = ((u64)k0 << 32) | (u32)(~n0); }
        if (k1 >= T) { u32 q = atomicAdd(&lc, 1u); buf[q] = ((u64)k1 << 32) | (u32)(~n1); }
    }
    __syncthreads();
    if (t == 0) gbase = atomicAdd(&meta[48 + b], lc);
    __syncthreads();
    u32 base = gbase, n = lc;
    for (u32 j = t; j < n; j += 256) {
        u32 d = base + j;
        if (d < CAP) cand[(size_t)b * CAP + d] = buf[j];
    }
}

// ---------------- cross-lane helpers ----------------
__device__ inline u64 shfl64(u64 x, int src) {
    int lo = __shfl((int)(u32)(x & 0xffffffffull), src, 64);
    int hi = __shfl((int)(u32)(x >> 32), src, 64);
    return ((u64)(u32)hi << 32) | (u32)lo;
}
__device__ inline u64 readlane64(u64 x, int sl) {
    u32 lo = (u32)__builtin_amdgcn_readlane((int)(u32)x, sl);
    u32 hi = (u32)__builtin_amdgcn_readlane((int)(u32)(x >> 32), sl);
    return ((u64)hi << 32) | lo;
}
__device__ inline u64 wave_or64(u64 x) {
    u32 lo = (u32)x, hi = (u32)(x >> 32);
    lo |= __builtin_amdgcn_ds_swizzle(lo, 0x041F); hi |= __builtin_amdgcn_ds_swizzle(hi, 0x041F);
    lo |= __builtin_amdgcn_ds_swizzle(lo, 0x081F); hi |= __builtin_amdgcn_ds_swizzle(hi, 0x081F);
    lo |= __builtin_amdgcn_ds_swizzle(lo, 0x101F); hi |= __builtin_amdgcn_ds_swizzle(hi, 0x101F);
    lo |= __builtin_amdgcn_ds_swizzle(lo, 0x201F); hi |= __builtin_amdgcn_ds_swizzle(hi, 0x201F);
    lo |= __builtin_amdgcn_ds_swizzle(lo, 0x401F); hi |= __builtin_amdgcn_ds_swizzle(hi, 0x401F);
    u32 l0 = (u32)__builtin_amdgcn_readlane((int)lo, 0)  | (u32)__builtin_amdgcn_readlane((int)lo, 32);
    u32 h0 = (u32)__builtin_amdgcn_readlane((int)hi, 0)  | (u32)__builtin_amdgcn_readlane((int)hi, 32);
    return ((u64)h0 << 32) | l0;
}

// ---------------- exact stable rank via 64-lane ring rotation; writes boxes+areas -------
__global__ void rank_kernel(const u64* __restrict__ cand, const u32* __restrict__ meta,
                            const float* __restrict__ anchors, const float* __restrict__ bbox,
                            float4* __restrict__ boxes, float* __restrict__ areas) {
    __shared__ u64 tile[2048];
    int b = blockIdx.y, t = threadIdx.x, l = t & 63;
    int c0 = blockIdx.x * 256 + t;
    u32 cnt = meta[48 + b]; if (cnt > CAP) cnt = CAP;
    if (blockIdx.x == 0 && t < ROWS - TOPK) {   // zero-pad rows 6000..6015
        boxes[(size_t)b * ROWS + TOPK + t] = make_float4(0.f, 0.f, 0.f, 0.f);
        areas[(size_t)b * ROWS + TOPK + t] = 0.f;
    }
    if (blockIdx.x * 256 >= (int)cnt) return;
    const u64* cb = cand + (size_t)b * CAP;
    u64 Kc = (c0 < (int)cnt) ? cb[c0] : 0ull;
    u32 rank = 0;
    for (u32 t0 = 0; t0 < cnt; t0 += 2048) {
        for (int q = t; q < 2048; q += 256)
            tile[q] = (t0 + (u32)q < cnt) ? cb[t0 + q] : 0ull;
        __syncthreads();
        u64 r[32];
        #pragma unroll
        for (int u = 0; u < 32; u++) r[u] = tile[l + (u << 6)];
        u64 kk = Kc; u32 cc = 0;
        for (int s = 0; s < 64; s++) {
            #pragma unroll
            for (int u = 0; u < 32; u++) cc += (r[u] > kk) ? 1u : 0u;
            int src = (l + 1) & 63;
            kk = shfl64(kk, src);
            cc = (u32)__shfl((int)cc, src, 64);
        }
        rank += cc;
        __syncthreads();
    }
    if (c0 < (int)cnt && rank < TOPK) {
        u32 idx = ~(u32)(Kc & 0xFFFFFFFFull);
        size_t off = ((size_t)b * NANCH + idx) * 4;
        const float4 a = *(const float4*)(anchors + off);
        const float4 d = *(const float4*)(bbox + off);
        float h = a.z - a.x, w = a.w - a.y;
        float cy = a.x + 0.5f * h, cx = a.y + 0.5f * w;
        float dy = d.x * 0.1f, dx = d.y * 0.1f, dh = d.z * 0.2f, dw = d.w * 0.2f;
        cy = cy + dy * h; cx = cx + dx * w;
        h = h * (float)exp((double)dh);
        w = w * (float)exp((double)dw);
        float y1 = cy - 0.5f * h, x1 = cx - 0.5f * w;
        float y2 = cy + 0.5f * h, x2 = cx + 0.5f * w;
        y1 = fminf(fmaxf(y1, 0.f), 1.f); x1 = fminf(fmaxf(x1, 0.f), 1.f);
        y2 = fminf(fmaxf(y2, 0.f), 1.f); x2 = fminf(fmaxf(x2, 0.f), 1.f);
        boxes[(size_t)b * ROWS + rank] = make_float4(y1, x1, y2, x2);
        areas[(size_t)b * ROWS + rank] = (y2 - y1) * (x2 - x1);  // same rounding as reference
    }
}

// ---------------- NMS phase A: mask only the first MROWS rows/cols (528 tiles) ----------
// Exact decision: RN(inter/uni) > 0.7f  <=>  inter >= MID*uni (reals), MID = 0.7f + 2^-25.
// Fast f32 path: d = fma(uni,-0.7f,inter); |d| > 2^-18*uni => sign decides. Waves with any
// borderline col (rare) redo the whole tile with an exact-sign f64 fma.
__global__ __launch_bounds__(256) void nms_mask_kernel(const float4* __restrict__ boxes,
                                                       const float* __restrict__ areas,
                                                       u64* __restrict__ Mt) {
    const float  EPS  = 3.8146972656e-06f;                       // 2^-18
    const double MIDD = (double)0.7f + 2.9802322387695312e-08;   // midpoint to nextup(0.7f)
    __shared__ float4 scol[4][64];
    __shared__ float  sare[4][64];
    int b = blockIdx.y;
    int wv = threadIdx.x >> 6, l = threadIdx.x & 63;
    int tid = blockIdx.x * 4 + wv;                               // linear upper-tri tile id
    if (tid >= NT2) return;                                      // wave-private LDS: safe
    // decode tid -> (cb, rt), rt <= cb, tid = cb*(cb+1)/2 + rt
    int cb = (int)((sqrt(8.0 * (double)tid + 1.0) - 1.0) * 0.5);
    while ((cb + 1) * (cb + 2) / 2 <= tid) cb++;
    while (cb * (cb + 1) / 2 > tid) cb--;
    int rt = tid - cb * (cb + 1) / 2;
    const float4* bx = boxes + (size_t)b * ROWS;
    const float*  ar = areas + (size_t)b * ROWS;
    scol[wv][l] = bx[cb * 64 + l];               // stage this wave's 64 col boxes (wave-sync)
    sare[wv][l] = ar[cb * 64 + l];
    int row = rt * 64 + l;
    float4 r4 = bx[row];
    float  rar = ar[row];
    u32 wlo = 0, whi = 0; u64 unc = 0;
    #pragma unroll
    for (int c = 63; c >= 0; c--) {              // full unroll, shift-or accumulation
        float4 c4 = scol[wv][c];                 // broadcast ds_read_b128 (no conflict)
        float  caf = sare[wv][c];
        float y1 = fmaxf(r4.x, c4.x), x1 = fmaxf(r4.y, c4.y);
        float y2 = fminf(r4.z, c4.z), x2 = fminf(r4.w, c4.w);
        float inter = fmaxf(y2 - y1, 0.f) * fmaxf(x2 - x1, 0.f);
        float uni = ((rar + caf) - inter) + 1e-9f;   // assoc matches reference
        float d = fmaf(uni, -0.7f, inter);
        float tt = uni * EPS;
        u32 sup = (d > tt) ? 1u : 0u;
        unc |= __ballot(fabsf(d) <= tt);
        if (c >= 32) whi = (whi << 1) | sup;
        else         wlo = (wlo << 1) | sup;
    }
    if (unc) {                                   // wave-uniform, rare
        wlo = 0; whi = 0;
        for (int c = 63; c >= 0; c--) {
            float4 c4 = scol[wv][c]; float caf = sare[wv][c];
            float y1 = fmaxf(r4.x, c4.x), x1 = fmaxf(r4.y, c4.y);
            float y2 = fminf(r4.z, c4.z), x2 = fminf(r4.w, c4.w);
            float inter = fmaxf(y2 - y1, 0.f) * fmaxf(x2 - x1, 0.f);
            float uni = ((rar + caf) - inter) + 1e-9f;
            double td = fma((double)uni, -MIDD, (double)inter);
            u32 sup = (td >= 0.0) ? 1u : 0u;     // exact sign; tie -> suppress (RN ties up)
            if (c >= 32) whi = (whi << 1) | sup;
            else         wlo = (wlo << 1) | sup;
        }
    }
    u64 w = ((u64)whi << 32) | wlo;
    if (cb == rt) w &= (l < 63) ? (~0ull << (l + 1)) : 0ull;   // cols > row only
    Mt[((size_t)b * MWORDS + cb) * MROWS + row] = w;           // coalesced full-line store
}

// ---------------- NMS phase B: masked sweep over first MROWS, exact fallback beyond -----
__global__ __launch_bounds__(64) void nms_seq_kernel(const float4* __restrict__ boxes,
                                                     const float* __restrict__ areas,
                                                     const u64* __restrict__ Mt,
                                                     float* __restrict__ out) {
    const double MIDD = (double)0.7f + 2.9802322387695312e-08;
    __shared__ u32 keptIdx[1024];
    __shared__ float4 sbox[1024];
    __shared__ float  skar[1024];
    int b = blockIdx.x, l = threadIdx.x;
    const u64* Mb = Mt + (size_t)b * MWORDS * MROWS;  // Mb[word*MROWS + row]
    const float4* bx = boxes + (size_t)b * ROWS;
    const float*  ar = areas + (size_t)b * ROWS;
    float4* ob = (float4*)(out + (size_t)b * OUTK * 4);
    int kept = 0;
    u64 rw = 0;
    u64 dw0 = Mb[l];                                  // diag word of chunk 0
    float4 vb0 = bx[l];  float va0 = ar[l];
    u64 X0 = Mb[(size_t)MROWS + l];                   // chunk-0 rows -> word 1
    u64 dw1 = Mb[(size_t)MROWS + 64 + l];             // diag word of chunk 1
    float4 vb1 = bx[64 + l]; float va1 = ar[64 + l];
    u64 X1 = Mb[(size_t)2 * MROWS + 64 + l];          // chunk-1 rows -> word 2
    u64 gp = 0;
    for (int c = 0; c < MWORDS; c++) {
        int base = c * 64;
        u64 alive = ~rw;                              // all MROWS rows valid (< TOPK)
        u64 km = 0, xk = 0; int kt = kept;
        while (alive && kt < OUTK) {                  // greedy: SALU/readlane only
            int j = __builtin_amdgcn_readfirstlane((int)__builtin_ctzll(alive));
            km |= 1ull << j; kt++;
            u64 dwj = readlane64(dw0, j);
            xk |= readlane64(X0, j);
            alive &= ~dwj & ~(1ull << j);
        }
        if ((km >> l) & 1) {
            int pos = kept + __popcll(km & ((1ull << l) - 1));
            ob[pos] = vb0;
            keptIdx[pos] = (u32)(base + l);
            sbox[pos] = vb0;                          // mirror for potential fallback
            skar[pos] = va0;
        }
        kept = kt;
        if (kept >= OUTK || c + 1 >= MWORDS) break;
        rw = xk | wave_or64(gp);
        __syncthreads();                              // keptIdx visible for gather
        u64 dw2 = 0, X2 = 0; float4 vb2 = make_float4(0.f, 0.f, 0.f, 0.f); float va2 = 0.f;
        u64 gpn = 0;
        if (c + 2 < MWORDS) {
            int nb2 = base + 128;
            dw2 = Mb[(size_t)(c + 2) * MROWS + nb2 + l];
            vb2 = bx[nb2 + l]; va2 = ar[nb2 + l];
            if (c + 3 < MWORDS) X2 = Mb[(size_t)(c + 3) * MROWS + nb2 + l];
            int K = kept;
            if (K > 0) {
                #pragma unroll
                for (int u = 0; u < 16; u++) {
                    int k = l + (u << 6);
                    u32 idx = keptIdx[(k < K) ? k : K - 1];
                    gpn |= Mb[(size_t)(c + 2) * MROWS + idx];
                }
            }
        }
        dw0 = dw1; X0 = X1; vb0 = vb1; va0 = va1;
        dw1 = dw2; X1 = X2; vb1 = vb2; va1 = va2;
        gp = gpn;
    }
    // exact on-demand fallback for rows beyond the masked window (expected never taken)
    if (kept < OUTK) {
        __syncthreads();
        for (int i = MROWS; i < TOPK && kept < OUTK; i++) {
            float4 c4 = bx[i]; float ca = ar[i];      // uniform load
            int sup = 0;
            for (int j = l; j < kept; j += 64) {
                float4 kb = sbox[j]; float ka = skar[j];
                float y1 = fmaxf(kb.x, c4.x), x1 = fmaxf(kb.y, c4.y);
                float y2 = fminf(kb.z, c4.z), x2 = fminf(kb.w, c4.w);
                float inter = fmaxf(y2 - y1, 0.f) * fmaxf(x2 - x1, 0.f);
                float uni = ((ka + ca) - inter) + 1e-9f;
                double td = fma((double)uni, -MIDD, (double)inter);
                sup |= (td >= 0.0) ? 1 : 0;
            }
            if (!__any(sup)) {
                if (l == 0) { ob[kept] = c4; sbox[kept] = c4; skar[kept] = ca; }
                kept++;
            }
        }
    }
    // tail zeros (replaces d_out memset): positions [kept, OUTK)
    for (int p = kept + l; p < OUTK; p += 64)
        ob[p] = make_float4(0.f, 0.f, 0.f, 0.f);
}

// ---------------- host ----------------
extern "C" void kernel_launch(void* const* d_in, const int* in_sizes, int n_in,
                              void* d_out, int out_size, void* d_ws, size_t ws_size,
                              hipStream_t stream) {
    const float* cls     = (const float*)d_in[0];   // rpn_class  (B,N,2)
    const float* bbox    = (const float*)d_in[1];   // rpn_bbox   (B,N,4)
    const float* anchors = (const float*)d_in[2];   // anchors    (B,N,4)

    char* ws = (char*)d_ws;
    u32* hist1 = (u32*)(ws);                        // 131072
    u32* meta  = (u32*)(ws + 131072);               // 256 B (count @48+b)
    float4* boxes = (float4*)(ws + 131328);         // 8*6016*16 = 770048 -> end 901376
    float* areas  = (float*)(ws + 901376);          // 8*6016*4  = 192512 -> end 1093888
    u64* Mt = (u64*)(ws + 1093888);                 // 8*32*2048*8 = 4194304 -> end 5288192
    u64* cand = Mt;                                 // overlay: cand (1 MB) dead before Mt written
    size_t need = 1093888 + (size_t)NBATCH * MWORDS * MROWS * 8;
    if (ws_size < need) return;

    hipMemsetAsync(ws, 0, 131328, stream);          // hist + meta

    hist_kernel<<<dim3(64, NBATCH), 256, 0, stream>>>(cls, hist1);
    compact_kernel<<<dim3(64, NBATCH), 256, 0, stream>>>(cls, hist1, meta, cand);
    rank_kernel<<<dim3(CAP / 256, NBATCH), 256, 0, stream>>>(cand, meta, anchors, bbox, boxes, areas);
    nms_mask_kernel<<<dim3((NT2 + 3) / 4, NBATCH), 256, 0, stream>>>(boxes, areas, Mt);
    nms_seq_kernel<<<NBATCH, 64, 0, stream>>>(boxes, areas, Mt, (float*)d_out);
}